// Round 5
// baseline (234.265 us; speedup 1.0000x reference)
//
#include <hip/hip_runtime.h>
#include <math.h>

// Problem constants
#define B_  2
#define S_  2048
#define E_  768
#define H_  12
#define HD_ 64
#define M_  (B_ * S_)     // 4096 rows
#define N3E (3 * E_)      // 2304

typedef __attribute__((ext_vector_type(8)))  short short8;    // 8 bf16 = 4 VGPRs
typedef __attribute__((ext_vector_type(4)))  float floatx4;   // 16x16 MFMA C/D
typedef __attribute__((ext_vector_type(16))) float floatx16;  // 32x32 MFMA C/D

// round-to-nearest-even fp32 -> bf16
__device__ inline unsigned short f2bf(float f) {
  union { float f; unsigned u; } a; a.f = f;
  unsigned r = a.u + 0x7fff + ((a.u >> 16) & 1);
  return (unsigned short)(r >> 16);
}
// round-half-up (2 VALU ops; still <= 0.5 ulp)
__device__ inline unsigned short f2bf_fast(float f) {
  union { float f; unsigned u; } a; a.f = f;
  return (unsigned short)((a.u + 0x8000u) >> 16);
}

// ---------------------------------------------------------------------------
// Kernel 0: fp32 -> bf16 weight conversion
// ---------------------------------------------------------------------------
__global__ __launch_bounds__(256) void cvt_kernel(
    const float* __restrict__ src, unsigned short* __restrict__ dst, int n4) {
  int i = blockIdx.x * 256 + threadIdx.x;
  if (i < n4) {
    float4 f = *(const float4*)&src[i * 4];
    ushort4 r;
    r.x = f2bf(f.x); r.y = f2bf(f.y); r.z = f2bf(f.z); r.w = f2bf(f.w);
    *(ushort4*)&dst[i * 4] = r;
  }
}

// ---------------------------------------------------------------------------
// Kernel 1: LayerNorm -> bf16 xn
// ---------------------------------------------------------------------------
__global__ __launch_bounds__(256) void ln_kernel(
    const float* __restrict__ x, const float* __restrict__ gamma,
    const float* __restrict__ beta, unsigned short* __restrict__ xnb) {
  const int row = blockIdx.x;
  const int t = threadIdx.x;
  const float* xr = x + (size_t)row * E_;

  float v0 = xr[t];
  float v1 = xr[t + 256];
  float v2 = xr[t + 512];
  float s  = v0 + v1 + v2;
  float s2 = v0 * v0 + v1 * v1 + v2 * v2;

  for (int o = 32; o > 0; o >>= 1) {
    s  += __shfl_down(s, o);
    s2 += __shfl_down(s2, o);
  }
  __shared__ float red[8];
  const int wave = t >> 6, lane = t & 63;
  if (lane == 0) { red[wave] = s; red[4 + wave] = s2; }
  __syncthreads();
  s  = red[0] + red[1] + red[2] + red[3];
  s2 = red[4] + red[5] + red[6] + red[7];

  const float mu  = s * (1.0f / E_);
  const float var = s2 * (1.0f / E_) - mu * mu;
  const float rs  = rsqrtf(var + 1e-5f);

  unsigned short* xo = xnb + (size_t)row * E_;
  xo[t]       = f2bf((v0 - mu) * rs * gamma[t]       + beta[t]);
  xo[t + 256] = f2bf((v1 - mu) * rs * gamma[t + 256] + beta[t + 256]);
  xo[t + 512] = f2bf((v2 - mu) * rs * gamma[t + 512] + beta[t + 512]);
}

// ---------------------------------------------------------------------------
// Kernel 2/4: bf16 MFMA GEMM  C[M][N] = A[M][768] * W[N][768]^T + bias[N]
// ---------------------------------------------------------------------------
__global__ __launch_bounds__(256) void bgemm_kernel(
    const unsigned short* __restrict__ A, const unsigned short* __restrict__ Wb,
    const float* __restrict__ bias, int mode,
    unsigned short* __restrict__ qbf, unsigned short* __restrict__ kbf,
    unsigned short* __restrict__ vtb, float* __restrict__ out) {
  __shared__ __align__(16) unsigned short As[128 * 64];
  __shared__ __align__(16) unsigned short Bs[128 * 64];

  const int t  = threadIdx.x;
  const int ln = t & 63, wv = t >> 6;
  const int lr = ln & 15, lg = ln >> 4;
  const int wr = wv >> 1, wc = wv & 1;
  const int m0 = blockIdx.x * 128, n0 = blockIdx.y * 128;

  const int srow = ln >> 3;
  const int scol = (ln & 7) * 8;

  const unsigned short* Ag = A  + (size_t)(m0 + wv * 32 + srow) * 768 + scol;
  const unsigned short* Bg = Wb + (size_t)(n0 + wv * 32 + srow) * 768 + scol;

  floatx4 acc[4][4];
#pragma unroll
  for (int i = 0; i < 4; i++)
#pragma unroll
    for (int j = 0; j < 4; j++) acc[i][j] = (floatx4){0.f, 0.f, 0.f, 0.f};

  for (int k0 = 0; k0 < 768; k0 += 64) {
    __syncthreads();
#pragma unroll
    for (int j = 0; j < 4; j++) {
      __builtin_amdgcn_global_load_lds(
          (const __attribute__((address_space(1))) void*)(Ag + k0 + j * 8 * 768),
          (__attribute__((address_space(3))) void*)(&As[(wv * 32 + j * 8) * 64]),
          16, 0, 0);
      __builtin_amdgcn_global_load_lds(
          (const __attribute__((address_space(1))) void*)(Bg + k0 + j * 8 * 768),
          (__attribute__((address_space(3))) void*)(&Bs[(wv * 32 + j * 8) * 64]),
          16, 0, 0);
    }
    __syncthreads();

#pragma unroll
    for (int kk = 0; kk < 2; kk++) {
      short8 af[4], bf[4];
#pragma unroll
      for (int i = 0; i < 4; i++)
        af[i] = *(const short8*)&As[(wr * 64 + i * 16 + lr) * 64 + kk * 32 + lg * 8];
#pragma unroll
      for (int j = 0; j < 4; j++)
        bf[j] = *(const short8*)&Bs[(wc * 64 + j * 16 + lr) * 64 + kk * 32 + lg * 8];
#pragma unroll
      for (int i = 0; i < 4; i++)
#pragma unroll
        for (int j = 0; j < 4; j++)
          acc[i][j] = __builtin_amdgcn_mfma_f32_16x16x32_bf16(af[i], bf[j], acc[i][j], 0, 0, 0);
    }
  }

  if (mode == 1) {
#pragma unroll
    for (int i = 0; i < 4; i++) {
      const int grow0 = m0 + wr * 64 + i * 16 + lg * 4;
#pragma unroll
      for (int j = 0; j < 4; j++) {
        const int gcol = n0 + wc * 64 + j * 16 + lr;
        const float bb = bias[gcol];
#pragma unroll
        for (int r = 0; r < 4; r++)
          out[(size_t)(grow0 + r) * E_ + gcol] = acc[i][j][r] + bb;
      }
    }
  } else {
#pragma unroll
    for (int i = 0; i < 4; i++) {
      const int grow0 = m0 + wr * 64 + i * 16 + lg * 4;
      const int bq = grow0 >> 11, s0 = grow0 & 2047;
#pragma unroll
      for (int j = 0; j < 4; j++) {
        const int n = n0 + wc * 64 + j * 16 + lr;
        const int h = n / 192, w = (n >> 6) % 3, d = n & 63;
        const int bh = bq * H_ + h;
        const float bb = bias[n];
        if (w == 2) {
          ushort4 rv;
          rv.x = f2bf(acc[i][j][0] + bb);
          rv.y = f2bf(acc[i][j][1] + bb);
          rv.z = f2bf(acc[i][j][2] + bb);
          rv.w = f2bf(acc[i][j][3] + bb);
          *(ushort4*)&vtb[((size_t)bh * HD_ + d) * S_ + s0] = rv;
        } else {
          unsigned short* dst = (w == 0) ? qbf : kbf;
          const float sc = (w == 0) ? 0.125f : 1.0f;
#pragma unroll
          for (int r = 0; r < 4; r++)
            dst[((size_t)bh * S_ + s0 + r) * HD_ + d] = f2bf((acc[i][j][r] + bb) * sc);
        }
      }
    }
  }
}

// ---------------------------------------------------------------------------
// Kernel 3: flash attention, 32x32x16 bf16 MFMA, operand-swapped:
//   S^T = K·Q^T,  O^T = V^T·P^T,  l = ones·P^T (same layout as O^T).
// All MFMA operands except P^T stream straight from global (L2-resident);
// P^T is wave-private LDS (no barriers in the K-loop at all).
// 4 waves: wq = wv&1 (q 32-row half), kh = wv>>1 (key 32-half); partial
// O/l of the kh pair combined once through LDS in the epilogue.
// Block = 64 q-rows x one head; grid 768 (XCD-swizzled: 3 heads per XCD).
// ---------------------------------------------------------------------------
#define PROW 40   // P^T row stride in shorts (80 B): b128 reads conflict-free

__global__ __launch_bounds__(256, 3) void attn_kernel(
    const unsigned short* __restrict__ qb, const unsigned short* __restrict__ kb,
    const unsigned short* __restrict__ vtb, unsigned short* __restrict__ ao) {
  __shared__ __align__(16) unsigned short Ps[4 * 32 * PROW];  // 10 KB, per-wave
  __shared__ __align__(16) float Cmb[2 * 64 * 36];            // 18 KB, combine

  const int t = threadIdx.x;
  const int lane = t & 63, wv = t >> 6;
  const int l31 = lane & 31, l5 = lane >> 5;
  const int wq = wv & 1, kh = wv >> 1;

  // XCD swizzle: consecutive blockIdx round-robin XCDs -> give each XCD 3 heads
  const int id = blockIdx.x;
  const int bh = (id & 7) * 3 + ((id >> 3) >> 5);
  const int qt = (id >> 3) & 31;
  const int b = bh / H_, h = bh % H_;
  const int q0 = qt * 64;
  const size_t base = (size_t)bh * S_ * HD_;

  // Q as B-operand (B[k=d][n=qrow]), resident: 4 chunks of 16 d
  short8 qf[4];
  {
    const unsigned short* qp = qb + base + (size_t)(q0 + wq * 32 + l31) * HD_ + l5 * 8;
#pragma unroll
    for (int kc = 0; kc < 4; kc++) qf[kc] = *(const short8*)(qp + kc * 16);
  }
  short8 ones;
#pragma unroll
  for (int i = 0; i < 8; i++) ones[i] = (short)0x3F80;  // bf16 1.0

  floatx16 oacc0 = (floatx16)0.0f;   // O^T d-block 0 (d = 0..31)
  floatx16 oacc1 = (floatx16)0.0f;   // O^T d-block 1 (d = 32..63)
  floatx16 lacc  = (floatx16)0.0f;   // softmax denominator (replicated)

  // K as A-operand (A[m=key][k=d]): row = t0 + kh*32 + l31
  const unsigned short* kp = kb + base + (size_t)(kh * 32 + l31) * HD_ + l5 * 8;
  // V^T as A-operand (A[m=d][k=key]): row = db*32 + l31, col = t0 + kh*32 ...
  const unsigned short* vp = vtb + base + (size_t)l31 * S_ + kh * 32 + l5 * 8;
  unsigned short* PsW = &Ps[wv * 32 * PROW];

  short8 kf[4];
#pragma unroll
  for (int kc = 0; kc < 4; kc++) kf[kc] = *(const short8*)(kp + kc * 16);

  for (int t0 = 0; t0 < S_; t0 += 64) {
    // V frags for this tile (issued early; independent of QK)
    short8 vf[4];
#pragma unroll
    for (int db = 0; db < 2; db++)
#pragma unroll
      for (int kc2 = 0; kc2 < 2; kc2++)
        vf[db * 2 + kc2] = *(const short8*)(vp + (size_t)db * 32 * S_ + kc2 * 16 + t0);

    // ---- S^T = K Q^T  (C/D: col = qrow = l31, row = key = (reg&3)+8*(reg>>2)+4*l5)
    floatx16 sacc = (floatx16)0.0f;
#pragma unroll
    for (int kc = 0; kc < 4; kc++)
      sacc = __builtin_amdgcn_mfma_f32_32x32x16_bf16(kf[kc], qf[kc], sacc, 0, 0, 0);

    // prefetch K frags for next tile (wraps harmlessly on last iter)
    const int tn = (t0 + 64) & (S_ - 1);
#pragma unroll
    for (int kc = 0; kc < 4; kc++)
      kf[kc] = *(const short8*)(kp + (size_t)tn * HD_ + kc * 16);

    // ---- p = exp(s); write P^T rows (row = qrow, lane-contiguous packs)
#pragma unroll
    for (int r = 0; r < 16; r++) sacc[r] = __expf(sacc[r]);
#pragma unroll
    for (int rq = 0; rq < 4; rq++) {
      ushort4 w;
      w.x = f2bf_fast(sacc[rq * 4 + 0]);
      w.y = f2bf_fast(sacc[rq * 4 + 1]);
      w.z = f2bf_fast(sacc[rq * 4 + 2]);
      w.w = f2bf_fast(sacc[rq * 4 + 3]);
      *(ushort4*)&PsW[l31 * PROW + rq * 8 + l5 * 4] = w;  // keys 8rq+4*l5..+3
    }

    // ---- read P^T as B-operand (B[k=key][n=qrow]); wave-private, no barrier
    const unsigned short* prd = &PsW[l31 * PROW + l5 * 8];
    short8 pf0 = *(const short8*)(prd);        // keys  0..15 chunk
    short8 pf1 = *(const short8*)(prd + 16);   // keys 16..31 chunk

    // ---- O^T += V^T P^T ;  l += ones·P^T
    oacc0 = __builtin_amdgcn_mfma_f32_32x32x16_bf16(vf[0], pf0, oacc0, 0, 0, 0);
    oacc0 = __builtin_amdgcn_mfma_f32_32x32x16_bf16(vf[1], pf1, oacc0, 0, 0, 0);
    oacc1 = __builtin_amdgcn_mfma_f32_32x32x16_bf16(vf[2], pf0, oacc1, 0, 0, 0);
    oacc1 = __builtin_amdgcn_mfma_f32_32x32x16_bf16(vf[3], pf1, oacc1, 0, 0, 0);
    lacc  = __builtin_amdgcn_mfma_f32_32x32x16_bf16(ones, pf0, lacc, 0, 0, 0);
    lacc  = __builtin_amdgcn_mfma_f32_32x32x16_bf16(ones, pf1, lacc, 0, 0, 0);
  }

  // ---- epilogue: combine kh halves (linear in keys), normalize, store
  float* cw = &Cmb[(size_t)(wq * 64 + lane) * 36];
  if (kh == 1) {
#pragma unroll
    for (int rq = 0; rq < 4; rq++) {
      float4 w0, w1;
      w0.x = oacc0[rq * 4 + 0]; w0.y = oacc0[rq * 4 + 1];
      w0.z = oacc0[rq * 4 + 2]; w0.w = oacc0[rq * 4 + 3];
      w1.x = oacc1[rq * 4 + 0]; w1.y = oacc1[rq * 4 + 1];
      w1.z = oacc1[rq * 4 + 2]; w1.w = oacc1[rq * 4 + 3];
      *(float4*)&cw[rq * 4]      = w0;
      *(float4*)&cw[16 + rq * 4] = w1;
    }
    cw[32] = lacc[0];
  }
  __syncthreads();
  if (kh == 0) {
    const float inv = 1.0f / (lacc[0] + cw[32]);
    const int row = q0 + wq * 32 + l31;
    unsigned short* arow = &ao[((size_t)(b * S_ + row)) * E_ + h * HD_];
#pragma unroll
    for (int rq = 0; rq < 4; rq++) {
      ushort4 s0, s1;
      s0.x = f2bf((oacc0[rq * 4 + 0] + cw[rq * 4 + 0]) * inv);
      s0.y = f2bf((oacc0[rq * 4 + 1] + cw[rq * 4 + 1]) * inv);
      s0.z = f2bf((oacc0[rq * 4 + 2] + cw[rq * 4 + 2]) * inv);
      s0.w = f2bf((oacc0[rq * 4 + 3] + cw[rq * 4 + 3]) * inv);
      s1.x = f2bf((oacc1[rq * 4 + 0] + cw[16 + rq * 4 + 0]) * inv);
      s1.y = f2bf((oacc1[rq * 4 + 1] + cw[16 + rq * 4 + 1]) * inv);
      s1.z = f2bf((oacc1[rq * 4 + 2] + cw[16 + rq * 4 + 2]) * inv);
      s1.w = f2bf((oacc1[rq * 4 + 3] + cw[16 + rq * 4 + 3]) * inv);
      // d = 8*rq + 4*l5 + i  (+32 for block 1)
      *(ushort4*)&arow[8 * rq + 4 * l5]      = s0;
      *(ushort4*)&arow[32 + 8 * rq + 4 * l5] = s1;
    }
  }
}

// ---------------------------------------------------------------------------
extern "C" void kernel_launch(void* const* d_in, const int* in_sizes, int n_in,
                              void* d_out, int out_size, void* d_ws, size_t ws_size,
                              hipStream_t stream) {
  const float* x     = (const float*)d_in[0];
  const float* gamma = (const float*)d_in[1];
  const float* beta  = (const float*)d_in[2];
  const float* Wqkv  = (const float*)d_in[3];
  const float* bqkv  = (const float*)d_in[4];
  const float* Wo    = (const float*)d_in[5];
  const float* bo    = (const float*)d_in[6];
  float* out = (float*)d_out;

  const size_t SZ = (size_t)M_ * E_;
  unsigned short* xnb = (unsigned short*)d_ws;
  unsigned short* qbf = xnb + SZ;
  unsigned short* kbf = qbf + SZ;
  unsigned short* vtb = kbf + SZ;
  unsigned short* aob = vtb + SZ;
  unsigned short* wqb = aob + SZ;
  unsigned short* wob = wqb + (size_t)N3E * E_;

  const int nq4 = (N3E * E_) / 4;
  const int no4 = (E_ * E_) / 4;
  cvt_kernel<<<(nq4 + 255) / 256, 256, 0, stream>>>(Wqkv, wqb, nq4);
  cvt_kernel<<<(no4 + 255) / 256, 256, 0, stream>>>(Wo, wob, no4);

  ln_kernel<<<M_, 256, 0, stream>>>(x, gamma, beta, xnb);

  dim3 g_qkv(M_ / 128, N3E / 128);  // (32, 18)
  bgemm_kernel<<<g_qkv, 256, 0, stream>>>(xnb, wqb, bqkv, 0, qbf, kbf, vtb, nullptr);

  attn_kernel<<<768, 256, 0, stream>>>(qbf, kbf, vtb, aob);

  dim3 g_out(M_ / 128, E_ / 128);   // (32, 6)
  bgemm_kernel<<<g_out, 256, 0, stream>>>(aob, wob, bo, 1, nullptr, nullptr, nullptr, out);
}

// Round 6
// 188.444 us; speedup vs baseline: 1.2432x; 1.2432x over previous
//
#include <hip/hip_runtime.h>
#include <math.h>

// Problem constants
#define B_  2
#define S_  2048
#define E_  768
#define H_  12
#define HD_ 64
#define M_  (B_ * S_)     // 4096 rows
#define N3E (3 * E_)      // 2304

typedef __attribute__((ext_vector_type(8)))  short short8;    // 8 bf16 = 4 VGPRs
typedef __attribute__((ext_vector_type(4)))  float floatx4;   // 16x16 MFMA C/D
typedef __attribute__((ext_vector_type(16))) float floatx16;  // 32x32 MFMA C/D

// fold 1/sqrt(64) * log2(e) into q so softmax is a bare v_exp_f32 (exp2)
#define QSCALE 0.18033688011112042f

// round-to-nearest-even fp32 -> bf16
__device__ inline unsigned short f2bf(float f) {
  union { float f; unsigned u; } a; a.f = f;
  unsigned r = a.u + 0x7fff + ((a.u >> 16) & 1);
  return (unsigned short)(r >> 16);
}
// round-half-up (2 VALU ops; still <= 0.5 ulp)
__device__ inline unsigned short f2bf_fast(float f) {
  union { float f; unsigned u; } a; a.f = f;
  return (unsigned short)((a.u + 0x8000u) >> 16);
}

// ---------------------------------------------------------------------------
// Kernel 0: fp32 -> bf16 weight conversion
// ---------------------------------------------------------------------------
__global__ __launch_bounds__(256) void cvt_kernel(
    const float* __restrict__ src, unsigned short* __restrict__ dst, int n4) {
  int i = blockIdx.x * 256 + threadIdx.x;
  if (i < n4) {
    float4 f = *(const float4*)&src[i * 4];
    ushort4 r;
    r.x = f2bf(f.x); r.y = f2bf(f.y); r.z = f2bf(f.z); r.w = f2bf(f.w);
    *(ushort4*)&dst[i * 4] = r;
  }
}

// ---------------------------------------------------------------------------
// Kernel 1: LayerNorm -> bf16 xn
// ---------------------------------------------------------------------------
__global__ __launch_bounds__(256) void ln_kernel(
    const float* __restrict__ x, const float* __restrict__ gamma,
    const float* __restrict__ beta, unsigned short* __restrict__ xnb) {
  const int row = blockIdx.x;
  const int t = threadIdx.x;
  const float* xr = x + (size_t)row * E_;

  float v0 = xr[t];
  float v1 = xr[t + 256];
  float v2 = xr[t + 512];
  float s  = v0 + v1 + v2;
  float s2 = v0 * v0 + v1 * v1 + v2 * v2;

  for (int o = 32; o > 0; o >>= 1) {
    s  += __shfl_down(s, o);
    s2 += __shfl_down(s2, o);
  }
  __shared__ float red[8];
  const int wave = t >> 6, lane = t & 63;
  if (lane == 0) { red[wave] = s; red[4 + wave] = s2; }
  __syncthreads();
  s  = red[0] + red[1] + red[2] + red[3];
  s2 = red[4] + red[5] + red[6] + red[7];

  const float mu  = s * (1.0f / E_);
  const float var = s2 * (1.0f / E_) - mu * mu;
  const float rs  = rsqrtf(var + 1e-5f);

  unsigned short* xo = xnb + (size_t)row * E_;
  xo[t]       = f2bf((v0 - mu) * rs * gamma[t]       + beta[t]);
  xo[t + 256] = f2bf((v1 - mu) * rs * gamma[t + 256] + beta[t + 256]);
  xo[t + 512] = f2bf((v2 - mu) * rs * gamma[t + 512] + beta[t + 512]);
}

// ---------------------------------------------------------------------------
// Kernel 2/4: bf16 MFMA GEMM  C[M][N] = A[M][768] * W[N][768]^T + bias[N]
// mode 0 epilogue emits q/k/v in MFMA-fragment-swizzled layouts so the
// attention kernel's fragment loads are base + lane*8 (fully coalesced):
//   q/k: [bh][tb][half][kc][lane][8]   (q pre-scaled by QSCALE)
//   v:   [bh][tb][kh][db][kc2][lane][8]
// mode 1: fp32 out[M][768] = C + bias
// ---------------------------------------------------------------------------
__global__ __launch_bounds__(256) void bgemm_kernel(
    const unsigned short* __restrict__ A, const unsigned short* __restrict__ Wb,
    const float* __restrict__ bias, int mode,
    unsigned short* __restrict__ qbf, unsigned short* __restrict__ kbf,
    unsigned short* __restrict__ vtb, float* __restrict__ out) {
  __shared__ __align__(16) unsigned short As[128 * 64];
  __shared__ __align__(16) unsigned short Bs[128 * 64];

  const int t  = threadIdx.x;
  const int ln = t & 63, wv = t >> 6;
  const int lr = ln & 15, lg = ln >> 4;
  const int wr = wv >> 1, wc = wv & 1;
  const int m0 = blockIdx.x * 128, n0 = blockIdx.y * 128;

  const int srow = ln >> 3;
  const int scol = (ln & 7) * 8;

  const unsigned short* Ag = A  + (size_t)(m0 + wv * 32 + srow) * 768 + scol;
  const unsigned short* Bg = Wb + (size_t)(n0 + wv * 32 + srow) * 768 + scol;

  floatx4 acc[4][4];
#pragma unroll
  for (int i = 0; i < 4; i++)
#pragma unroll
    for (int j = 0; j < 4; j++) acc[i][j] = (floatx4){0.f, 0.f, 0.f, 0.f};

  for (int k0 = 0; k0 < 768; k0 += 64) {
    __syncthreads();
#pragma unroll
    for (int j = 0; j < 4; j++) {
      __builtin_amdgcn_global_load_lds(
          (const __attribute__((address_space(1))) void*)(Ag + k0 + j * 8 * 768),
          (__attribute__((address_space(3))) void*)(&As[(wv * 32 + j * 8) * 64]),
          16, 0, 0);
      __builtin_amdgcn_global_load_lds(
          (const __attribute__((address_space(1))) void*)(Bg + k0 + j * 8 * 768),
          (__attribute__((address_space(3))) void*)(&Bs[(wv * 32 + j * 8) * 64]),
          16, 0, 0);
    }
    __syncthreads();

#pragma unroll
    for (int kk = 0; kk < 2; kk++) {
      short8 af[4], bf[4];
#pragma unroll
      for (int i = 0; i < 4; i++)
        af[i] = *(const short8*)&As[(wr * 64 + i * 16 + lr) * 64 + kk * 32 + lg * 8];
#pragma unroll
      for (int j = 0; j < 4; j++)
        bf[j] = *(const short8*)&Bs[(wc * 64 + j * 16 + lr) * 64 + kk * 32 + lg * 8];
#pragma unroll
      for (int i = 0; i < 4; i++)
#pragma unroll
        for (int j = 0; j < 4; j++)
          acc[i][j] = __builtin_amdgcn_mfma_f32_16x16x32_bf16(af[i], bf[j], acc[i][j], 0, 0, 0);
    }
  }

  if (mode == 1) {
#pragma unroll
    for (int i = 0; i < 4; i++) {
      const int grow0 = m0 + wr * 64 + i * 16 + lg * 4;
#pragma unroll
      for (int j = 0; j < 4; j++) {
        const int gcol = n0 + wc * 64 + j * 16 + lr;
        const float bb = bias[gcol];
#pragma unroll
        for (int r = 0; r < 4; r++)
          out[(size_t)(grow0 + r) * E_ + gcol] = acc[i][j][r] + bb;
      }
    }
  } else {
#pragma unroll
    for (int i = 0; i < 4; i++) {
      const int grow0 = m0 + wr * 64 + i * 16 + lg * 4;
      const int bq = grow0 >> 11, s0 = grow0 & 2047;
      const int tb = s0 >> 6, kh = (s0 >> 5) & 1;
#pragma unroll
      for (int j = 0; j < 4; j++) {
        const int n = n0 + wc * 64 + j * 16 + lr;
        const int h = n / 192, w = (n >> 6) % 3, d = n & 63;
        const int bh = bq * H_ + h;
        const float bb = bias[n];
        if (w == 2) {
          // V fragment layout: rows = keys s0..s0+3 -> e0..e0+3 within 8-pack
          const int db = d >> 5, l31v = d & 31;
          const int kc2 = (s0 >> 4) & 1, l5v = (s0 >> 3) & 1, e0 = s0 & 7;
          ushort4 rv;
          rv.x = f2bf(acc[i][j][0] + bb);
          rv.y = f2bf(acc[i][j][1] + bb);
          rv.z = f2bf(acc[i][j][2] + bb);
          rv.w = f2bf(acc[i][j][3] + bb);
          const size_t idx =
              ((((((size_t)bh * 32 + tb) * 2 + kh) * 2 + db) * 2 + kc2) * 2 + l5v) * 256
              + (size_t)l31v * 8 + e0;
          *(ushort4*)&vtb[idx] = rv;
        } else {
          unsigned short* dst = (w == 0) ? qbf : kbf;
          const float sc = (w == 0) ? QSCALE : 1.0f;
          const int kc = d >> 4, l5 = (d >> 3) & 1, e = d & 7;
          const size_t basei =
              ((((size_t)bh * 32 + tb) * 2 + kh) * 4 + kc) * 512 + (size_t)l5 * 256 + e;
          const int r0 = (s0 & 31) * 8;
#pragma unroll
          for (int r = 0; r < 4; r++)
            dst[basei + r0 + r * 8] = f2bf((acc[i][j][r] + bb) * sc);
        }
      }
    }
  }
}

// ---------------------------------------------------------------------------
// Kernel 3: flash attention, 32x32x16 bf16 MFMA, operand-swapped:
//   S^T = K·Q^T,  O^T = V^T·P^T,  l = ones·P^T.
// Q/K/V pre-swizzled to fragment order: every global fragment load is
// base + lane*8 (contiguous 1 KB per wave). No LDS staging, no barriers in
// the K-loop; P^T round-trips through wave-private LDS.
// Block = 64 q-rows x one head; grid 768, XCD-swizzled (3 heads per XCD).
// ---------------------------------------------------------------------------
#define PROW 40   // P^T row stride in shorts (80 B): b128 reads 16B-aligned

__global__ __launch_bounds__(256, 3) void attn_kernel(
    const unsigned short* __restrict__ qb, const unsigned short* __restrict__ kb,
    const unsigned short* __restrict__ vtb, unsigned short* __restrict__ ao) {
  __shared__ __align__(16) unsigned short Ps[4 * 32 * PROW];  // 10 KB, per-wave
  __shared__ __align__(16) float Cmb[2 * 64 * 36];            // 18 KB, combine

  const int t = threadIdx.x;
  const int lane = t & 63, wv = t >> 6;
  const int l31 = lane & 31, l5 = lane >> 5;
  const int wq = wv & 1, kh = wv >> 1;

  // XCD swizzle: id%8 round-robins XCDs -> 3 heads per XCD (1.5 MB K/V in L2)
  const int id = blockIdx.x;
  const int bh = (id & 7) * 3 + ((id >> 3) >> 5);
  const int qt = (id >> 3) & 31;
  const int b = bh / H_, h = bh % H_;
  const int q0 = qt * 64;

  // Q fragments (B-operand), resident: coalesced lane*8 loads
  short8 qf[4];
  {
    const unsigned short* qp =
        qb + ((((size_t)bh * 32 + qt) * 2 + wq) * 4) * 512 + (size_t)lane * 8;
#pragma unroll
    for (int kc = 0; kc < 4; kc++) qf[kc] = *(const short8*)(qp + kc * 512);
  }
  short8 ones;
#pragma unroll
  for (int i = 0; i < 8; i++) ones[i] = (short)0x3F80;  // bf16 1.0

  floatx16 oacc0 = (floatx16)0.0f;   // O^T d-block 0 (d = 0..31)
  floatx16 oacc1 = (floatx16)0.0f;   // O^T d-block 1 (d = 32..63)
  floatx16 lacc  = (floatx16)0.0f;   // softmax denominator (replicated)

  // fragment bases; per-tile stride 4096 elements
  const unsigned short* kpb = kb  + ((size_t)bh * 64 + kh) * 2048 + (size_t)lane * 8;
  const unsigned short* vpb = vtb + ((size_t)bh * 64 + kh) * 2048 + (size_t)lane * 8;
  unsigned short* PsW = &Ps[wv * 32 * PROW];

  short8 kf[4];
#pragma unroll
  for (int kc = 0; kc < 4; kc++) kf[kc] = *(const short8*)(kpb + kc * 512);

  for (int tb = 0; tb < 32; tb++) {
    // V frags for this tile (issued early; independent of QK)
    const unsigned short* vt = vpb + (size_t)tb * 4096;
    short8 vf0 = *(const short8*)(vt);           // db0, keys 0-15
    short8 vf1 = *(const short8*)(vt + 512);     // db0, keys 16-31
    short8 vf2 = *(const short8*)(vt + 1024);    // db1, keys 0-15
    short8 vf3 = *(const short8*)(vt + 1536);    // db1, keys 16-31

    // ---- S^T = K Q^T  (C/D: col = qrow = l31, row = key = (reg&3)+8*(reg>>2)+4*l5)
    floatx16 sacc = (floatx16)0.0f;
#pragma unroll
    for (int kc = 0; kc < 4; kc++)
      sacc = __builtin_amdgcn_mfma_f32_32x32x16_bf16(kf[kc], qf[kc], sacc, 0, 0, 0);

    // prefetch K frags for next tile (wraps harmlessly on last iter)
    {
      const unsigned short* kt = kpb + (size_t)((tb + 1) & 31) * 4096;
#pragma unroll
      for (int kc = 0; kc < 4; kc++) kf[kc] = *(const short8*)(kt + kc * 512);
    }

    // ---- p = exp2(s) (log2e folded into q); write P^T rows
#pragma unroll
    for (int r = 0; r < 16; r++) sacc[r] = exp2f(sacc[r]);
#pragma unroll
    for (int rq = 0; rq < 4; rq++) {
      ushort4 w;
      w.x = f2bf_fast(sacc[rq * 4 + 0]);
      w.y = f2bf_fast(sacc[rq * 4 + 1]);
      w.z = f2bf_fast(sacc[rq * 4 + 2]);
      w.w = f2bf_fast(sacc[rq * 4 + 3]);
      *(ushort4*)&PsW[l31 * PROW + rq * 8 + l5 * 4] = w;  // keys 8rq+4*l5..+3
    }

    // ---- read P^T as B-operand; wave-private, no barrier
    const unsigned short* prd = &PsW[l31 * PROW + l5 * 8];
    short8 pf0 = *(const short8*)(prd);        // keys  0..15
    short8 pf1 = *(const short8*)(prd + 16);   // keys 16..31

    // ---- O^T += V^T P^T ;  l += ones·P^T
    oacc0 = __builtin_amdgcn_mfma_f32_32x32x16_bf16(vf0, pf0, oacc0, 0, 0, 0);
    oacc0 = __builtin_amdgcn_mfma_f32_32x32x16_bf16(vf1, pf1, oacc0, 0, 0, 0);
    oacc1 = __builtin_amdgcn_mfma_f32_32x32x16_bf16(vf2, pf0, oacc1, 0, 0, 0);
    oacc1 = __builtin_amdgcn_mfma_f32_32x32x16_bf16(vf3, pf1, oacc1, 0, 0, 0);
    lacc  = __builtin_amdgcn_mfma_f32_32x32x16_bf16(ones, pf0, lacc, 0, 0, 0);
    lacc  = __builtin_amdgcn_mfma_f32_32x32x16_bf16(ones, pf1, lacc, 0, 0, 0);
  }

  // ---- epilogue: combine kh halves (linear in keys), normalize, store
  float* cw = &Cmb[(size_t)(wq * 64 + lane) * 36];
  if (kh == 1) {
#pragma unroll
    for (int rq = 0; rq < 4; rq++) {
      float4 w0, w1;
      w0.x = oacc0[rq * 4 + 0]; w0.y = oacc0[rq * 4 + 1];
      w0.z = oacc0[rq * 4 + 2]; w0.w = oacc0[rq * 4 + 3];
      w1.x = oacc1[rq * 4 + 0]; w1.y = oacc1[rq * 4 + 1];
      w1.z = oacc1[rq * 4 + 2]; w1.w = oacc1[rq * 4 + 3];
      *(float4*)&cw[rq * 4]      = w0;
      *(float4*)&cw[16 + rq * 4] = w1;
    }
    cw[32] = lacc[0];
  }
  __syncthreads();
  if (kh == 0) {
    const float inv = 1.0f / (lacc[0] + cw[32]);
    const int row = q0 + wq * 32 + l31;
    unsigned short* arow = &ao[((size_t)(b * S_ + row)) * E_ + h * HD_];
#pragma unroll
    for (int rq = 0; rq < 4; rq++) {
      ushort4 s0, s1;
      s0.x = f2bf((oacc0[rq * 4 + 0] + cw[rq * 4 + 0]) * inv);
      s0.y = f2bf((oacc0[rq * 4 + 1] + cw[rq * 4 + 1]) * inv);
      s0.z = f2bf((oacc0[rq * 4 + 2] + cw[rq * 4 + 2]) * inv);
      s0.w = f2bf((oacc0[rq * 4 + 3] + cw[rq * 4 + 3]) * inv);
      s1.x = f2bf((oacc1[rq * 4 + 0] + cw[16 + rq * 4 + 0]) * inv);
      s1.y = f2bf((oacc1[rq * 4 + 1] + cw[16 + rq * 4 + 1]) * inv);
      s1.z = f2bf((oacc1[rq * 4 + 2] + cw[16 + rq * 4 + 2]) * inv);
      s1.w = f2bf((oacc1[rq * 4 + 3] + cw[16 + rq * 4 + 3]) * inv);
      // d = 8*rq + 4*l5 + i  (+32 for block 1)
      *(ushort4*)&arow[8 * rq + 4 * l5]      = s0;
      *(ushort4*)&arow[32 + 8 * rq + 4 * l5] = s1;
    }
  }
}

// ---------------------------------------------------------------------------
extern "C" void kernel_launch(void* const* d_in, const int* in_sizes, int n_in,
                              void* d_out, int out_size, void* d_ws, size_t ws_size,
                              hipStream_t stream) {
  const float* x     = (const float*)d_in[0];
  const float* gamma = (const float*)d_in[1];
  const float* beta  = (const float*)d_in[2];
  const float* Wqkv  = (const float*)d_in[3];
  const float* bqkv  = (const float*)d_in[4];
  const float* Wo    = (const float*)d_in[5];
  const float* bo    = (const float*)d_in[6];
  float* out = (float*)d_out;

  const size_t SZ = (size_t)M_ * E_;
  unsigned short* xnb = (unsigned short*)d_ws;
  unsigned short* qbf = xnb + SZ;
  unsigned short* kbf = qbf + SZ;
  unsigned short* vtb = kbf + SZ;
  unsigned short* aob = vtb + SZ;
  unsigned short* wqb = aob + SZ;
  unsigned short* wob = wqb + (size_t)N3E * E_;

  const int nq4 = (N3E * E_) / 4;
  const int no4 = (E_ * E_) / 4;
  cvt_kernel<<<(nq4 + 255) / 256, 256, 0, stream>>>(Wqkv, wqb, nq4);
  cvt_kernel<<<(no4 + 255) / 256, 256, 0, stream>>>(Wo, wob, no4);

  ln_kernel<<<M_, 256, 0, stream>>>(x, gamma, beta, xnb);

  dim3 g_qkv(M_ / 128, N3E / 128);  // (32, 18)
  bgemm_kernel<<<g_qkv, 256, 0, stream>>>(xnb, wqb, bqkv, 0, qbf, kbf, vtb, nullptr);

  attn_kernel<<<768, 256, 0, stream>>>(qbf, kbf, vtb, aob);

  dim3 g_out(M_ / 128, E_ / 128);   // (32, 6)
  bgemm_kernel<<<g_out, 256, 0, stream>>>(aob, wob, bo, 1, nullptr, nullptr, nullptr, out);
}